// Round 12
// baseline (597.616 us; speedup 1.0000x reference)
//
#include <hip/hip_runtime.h>

constexpr int B = 8, S = 2048, D = 256;
constexpr float SCALE = 0.0625f;    // 1/sqrt(256)

typedef __attribute__((ext_vector_type(8))) short bf16x8;  // 8 bf16 in 4 VGPRs
typedef __attribute__((ext_vector_type(4))) float f32x4;

__device__ __forceinline__ short f2bf(float f) {
    union { float f; unsigned u; } c; c.f = f;
    unsigned u = c.u + 0x7fffu + ((c.u >> 16) & 1u);   // RNE
    return (short)(u >> 16);
}

// ---- pre-pass: convQ | convK | transposeV | zero-rsum in ONE launch ----
// grid: [0,4096) convQ, [4096,8192) convK, [8192,9216) transposeV,
//       [9216,9232) zero rsum (16 blk x 256 thr x float4 = 16384 floats)
__global__ __launch_bounds__(256) void prepass(
    const float* __restrict__ q, const float* __restrict__ k,
    const float* __restrict__ v,
    short* __restrict__ qb, short* __restrict__ kb,
    short* __restrict__ vtb, float* __restrict__ rsumg)
{
    __shared__ float tile[64][65];
    const int blk = blockIdx.x;
    const int tid = threadIdx.x;

    if (blk < 8192) {
        const float* in = (blk < 4096) ? q : k;
        short* out = (blk < 4096) ? qb : kb;
        int i = (blk & 4095) * 256 + tid;
        float4 x = ((const float4*)in)[i];
        short4 o; o.x = f2bf(x.x); o.y = f2bf(x.y); o.z = f2bf(x.z); o.w = f2bf(x.w);
        ((short4*)out)[i] = o;
    } else if (blk < 9216) {
        int blk2 = blk - 8192;
        int b = blk2 >> 7, rem = blk2 & 127;
        int d0 = (rem & 3) * 64, k0 = (rem >> 2) * 64;
        int tr = tid >> 4, tc = tid & 15;
        const float* vb = v + (size_t)b * S * D;
        #pragma unroll
        for (int r = 0; r < 4; ++r) {
            int key = r * 16 + tr;
            float4 x = *(const float4*)(vb + (size_t)(k0 + key) * D + d0 + tc * 4);
            tile[key][tc * 4 + 0] = x.x; tile[key][tc * 4 + 1] = x.y;
            tile[key][tc * 4 + 2] = x.z; tile[key][tc * 4 + 3] = x.w;
        }
        __syncthreads();
        short* vtbb = vtb + (size_t)b * D * S;
        #pragma unroll
        for (int r = 0; r < 4; ++r) {
            int d = r * 16 + tr;
            short4 o;
            o.x = f2bf(tile[tc * 4 + 0][d]); o.y = f2bf(tile[tc * 4 + 1][d]);
            o.z = f2bf(tile[tc * 4 + 2][d]); o.w = f2bf(tile[tc * 4 + 3][d]);
            *(short4*)(vtbb + (size_t)(d0 + d) * S + k0 + tc * 4) = o;
        }
    } else {
        int t = (blk - 9216) * 256 + tid;        // 0..4095 float4s = 16384 floats
        ((float4*)rsumg)[t] = float4{0.f, 0.f, 0.f, 0.f};
    }
}

// ---- kernel A: scores. grid 4096 = (kt 0..7) x (qt 0..63) x (b 0..7, low bits) ----
// Block = 32 q-rows x 256 keys. Wave = 32x32 tile -> acc is 16 regs, NO slab,
// NO LDS, NO barriers. Writes UNNORMALIZED exp scores (fp32, float4/lane) and
// atomicAdd row partial sums. High occupancy (small regs, 16 blocks/CU queued)
// gives the mask-in/attn-out streams memcpy-class TLP for the first time.
// Swapped MFMA (R7): C row = key, col = q -> float4 stores along k.
// XCD-batch affinity (R5): batch = blk & 7 keeps K_b/Q_b L2-resident.
__global__ __launch_bounds__(512) void attn_scores(
    const short* __restrict__ qb, const short* __restrict__ kb,
    const int* __restrict__ maskg, float* __restrict__ attng,
    float* __restrict__ rsumg)
{
    const int blk = blockIdx.x;
    const int b = blk & 7;
    const int qt = (blk >> 3) & 63;
    const int kt = blk >> 9;
    const int i0 = qt * 32, kq = kt * 256;
    const int tid = threadIdx.x;
    const int wave = tid >> 6, lane = tid & 63;
    const int quad = lane >> 4, l16 = lane & 15;
    const int k0w = kq + wave * 32;            // this wave's 32-key window

    // mask: 4 int4 loads (16 B/lane), issued before compute
    const int* mbase = maskg + ((size_t)b * S + i0 + l16) * S + k0w + quad * 4;
    int4 m00 = *(const int4*)(mbase);
    int4 m01 = *(const int4*)(mbase + 16);
    int4 m10 = *(const int4*)(mbase + (size_t)16 * S);
    int4 m11 = *(const int4*)(mbase + (size_t)16 * S + 16);

    const short* q0 = qb + ((size_t)b * S + i0 + l16) * D + quad * 8;
    const short* q1 = q0 + (size_t)16 * D;
    const short* k0p = kb + ((size_t)b * S + k0w + l16) * D + quad * 8;
    const short* k1p = k0p + (size_t)16 * D;

    f32x4 acc[2][2];
    #pragma unroll
    for (int mt = 0; mt < 2; ++mt)
        #pragma unroll
        for (int nt = 0; nt < 2; ++nt)
            acc[mt][nt] = f32x4{0.f, 0.f, 0.f, 0.f};

    #pragma unroll
    for (int ks = 0; ks < 8; ++ks) {
        bf16x8 a0 = *(const bf16x8*)(q0 + ks * 32);
        bf16x8 a1 = *(const bf16x8*)(q1 + ks * 32);
        bf16x8 b0 = *(const bf16x8*)(k0p + ks * 32);
        bf16x8 b1 = *(const bf16x8*)(k1p + ks * 32);
        acc[0][0] = __builtin_amdgcn_mfma_f32_16x16x32_bf16(b0, a0, acc[0][0], 0, 0, 0);
        acc[0][1] = __builtin_amdgcn_mfma_f32_16x16x32_bf16(b1, a0, acc[0][1], 0, 0, 0);
        acc[1][0] = __builtin_amdgcn_mfma_f32_16x16x32_bf16(b0, a1, acc[1][0], 0, 0, 0);
        acc[1][1] = __builtin_amdgcn_mfma_f32_16x16x32_bf16(b1, a1, acc[1][1], 0, 0, 0);
    }

    // mask + exp (unnormalized; exp(-1e9)->0 == reference) + row partial sums
    const int mm[2][2][4] = {
        {{m00.x, m00.y, m00.z, m00.w}, {m01.x, m01.y, m01.z, m01.w}},
        {{m10.x, m10.y, m10.z, m10.w}, {m11.x, m11.y, m11.z, m11.w}}};
    float rs[2] = {0.f, 0.f};
    #pragma unroll
    for (int mt = 0; mt < 2; ++mt)
        #pragma unroll
        for (int nt = 0; nt < 2; ++nt)
            #pragma unroll
            for (int r = 0; r < 4; ++r) {
                float e = mm[mt][nt][r] ? __expf(acc[mt][nt][r] * SCALE) : 0.0f;
                acc[mt][nt][r] = e;
                rs[mt] += e;
            }

    // reduce over the 4 quads sharing a row, one atomicAdd per row per wave
    #pragma unroll
    for (int mt = 0; mt < 2; ++mt) {
        float v = rs[mt];
        v += __shfl_xor(v, 16); v += __shfl_xor(v, 32);
        if (quad == 0)
            atomicAdd(rsumg + (size_t)b * S + i0 + mt * 16 + l16, v);
    }

    // store unnormalized scores: float4/lane; the two nt stores per row are
    // back-to-back 64 B halves of one 128 B line (R3/R9 batching law)
    #pragma unroll
    for (int mt = 0; mt < 2; ++mt) {
        float* arow = attng + ((size_t)b * S + i0 + mt * 16 + l16) * S + k0w + quad * 4;
        #pragma unroll
        for (int nt = 0; nt < 2; ++nt) {
            float4 p4;
            p4.x = acc[mt][nt][0]; p4.y = acc[mt][nt][1];
            p4.z = acc[mt][nt][2]; p4.w = acc[mt][nt][3];
            *(float4*)(arow + nt * 16) = p4;
        }
    }
}

// ---- kernel B: PV + in-place normalize. grid 512 = (qt 0..63) x (b, low bits) ----
// Phase 1: PV-MFMA reading RAW scores from global (L2-hot 256 KB slab shared by
// the 8 waves), scaled by 1/rsum in-register before bf16 cvt. NO p_lds.
// __syncthreads. Phase 2: normalize attn in place (wave w owns cols
// [w*256,w*256+256); R8's proven batched float4 pattern), then store out.
__global__ __launch_bounds__(512) void attn_pv(
    float* __restrict__ attng, const float* __restrict__ rsumg,
    const short* __restrict__ vtb, float* __restrict__ outg)
{
    const int blk = blockIdx.x;
    const int b = blk & 7;
    const int i0 = (blk >> 3) * 32;
    const int tid = threadIdx.x;
    const int wave = tid >> 6, lane = tid & 63;
    const int quad = lane >> 4, l16 = lane & 15;

    float inv[2];
    inv[0] = 1.0f / rsumg[(size_t)b * S + i0 + l16];
    inv[1] = 1.0f / rsumg[(size_t)b * S + i0 + 16 + l16];

    // ---------- phase 1: out = P V, P = raw * inv (wave w owns dims [w*32, w*32+32)) ----------
    f32x4 oacc[2][2];
    #pragma unroll
    for (int mt = 0; mt < 2; ++mt)
        #pragma unroll
        for (int nc = 0; nc < 2; ++nc) oacc[mt][nc] = f32x4{0.f, 0.f, 0.f, 0.f};

    const short* vbase = vtb + (size_t)b * D * S;
    const int nb = wave * 32;
    const float* arow0 = attng + ((size_t)b * S + i0 + l16) * S + quad * 8;
    const float* arow1 = arow0 + (size_t)16 * S;
    const short* v0p = vbase + (size_t)(nb + l16) * S + quad * 8;
    const short* v1p = v0p + (size_t)16 * S;

    for (int ks = 0; ks < 64; ++ks) {
        float4 pa0a = *(const float4*)(arow0 + ks * 32);
        float4 pa0b = *(const float4*)(arow0 + ks * 32 + 4);
        float4 pa1a = *(const float4*)(arow1 + ks * 32);
        float4 pa1b = *(const float4*)(arow1 + ks * 32 + 4);
        bf16x8 ap0, ap1;
        ap0[0] = f2bf(pa0a.x * inv[0]); ap0[1] = f2bf(pa0a.y * inv[0]);
        ap0[2] = f2bf(pa0a.z * inv[0]); ap0[3] = f2bf(pa0a.w * inv[0]);
        ap0[4] = f2bf(pa0b.x * inv[0]); ap0[5] = f2bf(pa0b.y * inv[0]);
        ap0[6] = f2bf(pa0b.z * inv[0]); ap0[7] = f2bf(pa0b.w * inv[0]);
        ap1[0] = f2bf(pa1a.x * inv[1]); ap1[1] = f2bf(pa1a.y * inv[1]);
        ap1[2] = f2bf(pa1a.z * inv[1]); ap1[3] = f2bf(pa1a.w * inv[1]);
        ap1[4] = f2bf(pa1b.x * inv[1]); ap1[5] = f2bf(pa1b.y * inv[1]);
        ap1[6] = f2bf(pa1b.z * inv[1]); ap1[7] = f2bf(pa1b.w * inv[1]);
        bf16x8 bv0 = *(const bf16x8*)(v0p + ks * 32);
        bf16x8 bv1 = *(const bf16x8*)(v1p + ks * 32);
        oacc[0][0] = __builtin_amdgcn_mfma_f32_16x16x32_bf16(ap0, bv0, oacc[0][0], 0, 0, 0);
        oacc[0][1] = __builtin_amdgcn_mfma_f32_16x16x32_bf16(ap0, bv1, oacc[0][1], 0, 0, 0);
        oacc[1][0] = __builtin_amdgcn_mfma_f32_16x16x32_bf16(ap1, bv0, oacc[1][0], 0, 0, 0);
        oacc[1][1] = __builtin_amdgcn_mfma_f32_16x16x32_bf16(ap1, bv1, oacc[1][1], 0, 0, 0);
    }

    // all waves must finish reading RAW attn before any wave rewrites it
    __syncthreads();

    // ---------- phase 2: normalize attn in place (wave w owns cols [w*256, w*256+256)) ----------
    #pragma unroll
    for (int mt = 0; mt < 2; ++mt) {
        float* arow = attng + ((size_t)b * S + i0 + mt * 16 + l16) * S + wave * 256 + quad * 4;
        #pragma unroll
        for (int nt = 0; nt < 16; ++nt) {
            float4 t = *(const float4*)(arow + nt * 16);
            t.x *= inv[mt]; t.y *= inv[mt]; t.z *= inv[mt]; t.w *= inv[mt];
            *(float4*)(arow + nt * 16) = t;
        }
    }

    // out store (verified fragment layout from R8 phase C)
    #pragma unroll
    for (int mt = 0; mt < 2; ++mt)
        #pragma unroll
        for (int nc = 0; nc < 2; ++nc)
            #pragma unroll
            for (int r = 0; r < 4; ++r) {
                int row = i0 + mt * 16 + quad * 4 + r;
                int col = nb + nc * 16 + l16;
                outg[((size_t)b * S + row) * D + col] = oacc[mt][nc][r];
            }
}

extern "C" void kernel_launch(void* const* d_in, const int* in_sizes, int n_in,
                              void* d_out, int out_size, void* d_ws, size_t ws_size,
                              hipStream_t stream) {
    const float* q    = (const float*)d_in[0];
    const float* k    = (const float*)d_in[1];
    const float* v    = (const float*)d_in[2];
    const int*   mask = (const int*)d_in[3];
    float* out  = (float*)d_out;
    float* attn = out + (size_t)B * S * D;     // tuple order: (out, attn)

    const size_t N = (size_t)B * S * D;        // 4,194,304 elements
    short* qb  = (short*)d_ws;                 // 8 MB
    short* kb  = qb + N;                       // 8 MB
    short* vtb = kb + N;                       // 8 MB (transposed V)
    float* rsumg = (float*)(vtb + N);          // 64 KB row sums

    prepass<<<dim3(9232), 256, 0, stream>>>(q, k, v, qb, kb, vtb, rsumg);
    attn_scores<<<dim3(4096), 512, 0, stream>>>(qb, kb, mask, attn, rsumg);
    attn_pv<<<dim3(512), 512, 0, stream>>>(attn, rsumg, vtb, out);
}